// Round 8
// baseline (677.208 us; speedup 1.0000x reference)
//
#include <hip/hip_runtime.h>
#include <math.h>

typedef _Float16 hlf4 __attribute__((ext_vector_type(4)));
typedef _Float16 hlf8 __attribute__((ext_vector_type(8)));
typedef float f32x4 __attribute__((ext_vector_type(4)));

// async global->LDS, 16B per lane; lds base must be wave-uniform
static __device__ __forceinline__ void gl_lds16(const void* g, void* l) {
    __builtin_amdgcn_global_load_lds(
        (const __attribute__((address_space(1))) unsigned int*)g,
        (__attribute__((address_space(3))) unsigned int*)l, 16, 0, 0);
}

// ---------------- block reductions (deterministic tree order) ----------------
static __device__ __forceinline__ float blk_sum(float v) {
    __shared__ float sm[256];
    int tid = threadIdx.x;
    sm[tid] = v; __syncthreads();
#pragma unroll
    for (int s = 128; s > 0; s >>= 1) {
        if (tid < s) sm[tid] += sm[tid + s];
        __syncthreads();
    }
    float r = sm[0]; __syncthreads();
    return r;
}

static __device__ __forceinline__ float blk_max(float v) {
    __shared__ float sm[256];
    int tid = threadIdx.x;
    sm[tid] = v; __syncthreads();
#pragma unroll
    for (int s = 128; s > 0; s >>= 1) {
        if (tid < s) sm[tid] = fmaxf(sm[tid], sm[tid + s]);
        __syncthreads();
    }
    float r = sm[0]; __syncthreads();
    return r;
}

// ---------------- C normalizer: per-row norms of gathered rows ----------------
__global__ __launch_bounds__(256) void k_row_norms(
    const float* __restrict__ X, const int* __restrict__ idx,
    float* __restrict__ norms, int n) {
    long long r = idx[blockIdx.x];
    const float* xr = X + r * (long long)n;
    float s = 0.f;
    for (int k = threadIdx.x * 4; k < n; k += 256 * 4) {
        float4 v = *(const float4*)(xr + k);
        s = fmaf(v.x, v.x, s); s = fmaf(v.y, v.y, s);
        s = fmaf(v.z, v.z, s); s = fmaf(v.w, v.w, s);
    }
    float tot = blk_sum(s);
    if (threadIdx.x == 0) norms[blockIdx.x] = sqrtf(tot);
}

__global__ __launch_bounds__(256) void k_cinv(
    const float* __restrict__ norms, int m, int n, float* __restrict__ cinv) {
    float s = 0.f;
    for (int i = threadIdx.x; i < m; i += 256) s += norms[i];
    float tot = blk_sum(s);
    if (threadIdx.x == 0) cinv[0] = (float)m * sqrtf((float)n) / tot;  // 1/C
}

// ------- xs = x * (1/C) f32 (output) + UNSCALED f16 copy (LN-invariant) -----
__global__ __launch_bounds__(256) void k_scale2(
    const float* __restrict__ x, const float* __restrict__ cinv,
    float* __restrict__ y, _Float16* __restrict__ yh, long long total4) {
    float c = cinv[0];
    long long i = blockIdx.x * 256ll + threadIdx.x;
    long long stride = (long long)gridDim.x * 256ll;
    for (; i < total4; i += stride) {
        float4 v = ((const float4*)x)[i];
        float4 w = {v.x * c, v.y * c, v.z * c, v.w * c};
        ((float4*)y)[i] = w;
        // q = LN(xs@Wq^T) is invariant to the 1/C scale (LN scale-invariance,
        // eps shift ~1e-7 relative) -> store unscaled f16 for the q GEMM.
        hlf4 o = {(_Float16)v.x, (_Float16)v.y, (_Float16)v.z, (_Float16)v.w};
        ((hlf4*)yh)[i] = o;
    }
}

// -------- gather + cvt (NO 1/C scale: k,v are LN-invariant to it) -----------
__global__ __launch_bounds__(256) void k_gather_cvt(
    const float* __restrict__ X, const int* __restrict__ idx,
    _Float16* __restrict__ out, int n) {
    long long r = idx[blockIdx.x];
    const float* src = X + r * (long long)n;
    _Float16* dst = out + (long long)blockIdx.x * n;
    for (int k = threadIdx.x * 4; k < n; k += 256 * 4) {
        float4 v = *(const float4*)(src + k);
        hlf4 o = {(_Float16)v.x, (_Float16)v.y, (_Float16)v.z, (_Float16)v.w};
        *(hlf4*)(dst + k) = o;
    }
}

// ---------------- flat f32 -> f16 with scalar scale ----------------
__global__ __launch_bounds__(256) void k_cvt(
    const float* __restrict__ in, _Float16* __restrict__ out, long long n4,
    float sc) {
    long long i = blockIdx.x * 256ll + threadIdx.x;
    long long stride = (long long)gridDim.x * 256ll;
    for (; i < n4; i += stride) {
        float4 v = ((const float4*)in)[i];
        hlf4 o = {(_Float16)(v.x * sc), (_Float16)(v.y * sc),
                  (_Float16)(v.z * sc), (_Float16)(v.w * sc)};
        ((hlf4*)out)[i] = o;
    }
}

// ---------------- transpose + cvt: in[R][Cc] f32 -> out[Cc][R] f16 ----------
__global__ __launch_bounds__(256) void k_tcvt(
    const float* __restrict__ in, _Float16* __restrict__ out, int R, int Cc) {
    __shared__ _Float16 t[32][34];
    int tx = threadIdx.x & 31, ty = threadIdx.x >> 5;   // ty 0..7
    int c0 = blockIdx.x * 32, r0 = blockIdx.y * 32;
#pragma unroll
    for (int i = 0; i < 32; i += 8)
        t[ty + i][tx] = (_Float16)in[(long long)(r0 + ty + i) * Cc + c0 + tx];
    __syncthreads();
#pragma unroll
    for (int i = 0; i < 32; i += 8)
        out[(long long)(c0 + ty + i) * R + r0 + tx] = t[tx][ty + i];
}

// ================= m97-structure MFMA NT GEMM (128² tile, 4 waves) ==========
// Known-good R4 kernel; used for the small q/k projections.
__global__ __launch_bounds__(256) void k_gemm4(
    const _Float16* __restrict__ A, int lda,
    const _Float16* __restrict__ B, int ldb,
    float* __restrict__ Cc, long long ldc, int K,
    float* __restrict__ part, long long zstride) {
    __shared__ _Float16 Ah[2][4096];
    __shared__ _Float16 Bh[2][4096];
    const int tid = threadIdx.x;
    const long long m0 = (long long)blockIdx.x * 128;
    const long long n0 = (long long)blockIdx.y * 128;
    const int KC = K / gridDim.z;
    const int kbase = blockIdx.z * KC;
    const int lane = tid & 63, wv = tid >> 6;
    const int wm = (wv >> 1) * 64, wn = (wv & 1) * 64;
    const int fr = lane & 15, fq = lane >> 4;

    const int s0 = tid, s1 = tid + 256;
    const int r0s = s0 >> 2, r1s = s1 >> 2;
    const int g0 = (((s0 & 3) ^ (r0s & 3)) << 3);
    const int g1 = (((s1 & 3) ^ (r1s & 3)) << 3);
    const _Float16* A0 = A + (m0 + r0s) * (long long)lda + kbase + g0;
    const _Float16* A1 = A + (m0 + r1s) * (long long)lda + kbase + g1;
    const _Float16* B0 = B + (n0 + r0s) * (long long)ldb + kbase + g0;
    const _Float16* B1 = B + (n0 + r1s) * (long long)ldb + kbase + g1;

    f32x4 acc[4][4] = {};

    const int NT = KC / 32;
    {
        gl_lds16(A0, &Ah[0][wv * 512]);
        gl_lds16(A1, &Ah[0][2048 + wv * 512]);
        gl_lds16(B0, &Bh[0][wv * 512]);
        gl_lds16(B1, &Bh[0][2048 + wv * 512]);
    }
    __syncthreads();

    for (int kt = 0; kt < NT; ++kt) {
        const int cur = kt & 1;
        if (kt + 1 < NT) {
            const int nx = cur ^ 1;
            const long long ko = (long long)(kt + 1) * 32;
            gl_lds16(A0 + ko, &Ah[nx][wv * 512]);
            gl_lds16(A1 + ko, &Ah[nx][2048 + wv * 512]);
            gl_lds16(B0 + ko, &Bh[nx][wv * 512]);
            gl_lds16(B1 + ko, &Bh[nx][2048 + wv * 512]);
        }
        hlf8 af[4], bf[4];
#pragma unroll
        for (int i = 0; i < 4; ++i) {
            const int r = wm + i * 16 + fr;
            af[i] = *(const hlf8*)&Ah[cur][r * 32 + ((fq ^ (r & 3)) << 3)];
        }
#pragma unroll
        for (int j = 0; j < 4; ++j) {
            const int r = wn + j * 16 + fr;
            bf[j] = *(const hlf8*)&Bh[cur][r * 32 + ((fq ^ (r & 3)) << 3)];
        }
#pragma unroll
        for (int i = 0; i < 4; ++i)
#pragma unroll
            for (int j = 0; j < 4; ++j)
                acc[i][j] = __builtin_amdgcn_mfma_f32_16x16x32_f16(af[i], bf[j], acc[i][j], 0, 0, 0);
        __syncthreads();
    }

    float* outp = (gridDim.z == 1) ? Cc : (part + (long long)blockIdx.z * zstride);
#pragma unroll
    for (int i = 0; i < 4; ++i)
#pragma unroll
        for (int j = 0; j < 4; ++j) {
            float* cp = outp + (m0 + wm + i * 16 + fq * 4) * ldc + (n0 + wn + j * 16 + fr);
#pragma unroll
            for (int r = 0; r < 4; ++r) cp[(long long)r * ldc] = acc[i][j][r];
        }
}

// ========== 256² ring-4 pipelined NT GEMM (T4 counted vmcnt) ================
// C = A·B^T.  BM=BN=256, BK=32, 512 thr / 8 waves (2Mx4N, 128x64 each).
// LDS: 4-deep ring of (A 16KB + B 16KB) = 128 KiB. Per K-tile:
//   counted s_waitcnt vmcnt(8)  (4 at NT-2, 0 at NT-1 — never drains mid-loop)
//   raw s_barrier (ONLY barrier per tile; also licenses re-staging buf kt-1)
//   issue 4 global_load_lds for tile kt+3  (3-deep prefetch)
//   12 plain ds_read_b128 + 32 MFMA, compiler fine-schedules lgkmcnt;
//   single barrier/tile -> wave skew overlaps one wave's reads w/ another's MFMA.
// Tile layout [128 Lrows][64 halfs]: global row r at Lrow r&127, col-half
// (r>>7); 8 phys 16B-slots/row, slot p holds k-group (p^(L&7)) (R6-verified
// 0-conflict XOR swizzle, both sides per rule 21).
// OUT16=1: epilogue converts acc to f16 into (hlf*)Cc.
template <int OUT16>
__global__ __launch_bounds__(512) void k_g256(
    const _Float16* __restrict__ A, int lda,
    const _Float16* __restrict__ B, int ldb,
    void* __restrict__ Cc, long long ldc, int K,
    float* __restrict__ part, long long zstride) {
    __shared__ _Float16 Ah[4][8192];
    __shared__ _Float16 Bh[4][8192];
    const int tid = threadIdx.x, lane = tid & 63, wv = tid >> 6;

    // XCD-aware bijective remap (all launches keep nwg % 8 == 0)
    const int gx = gridDim.x, gy = gridDim.y;
    int lin = blockIdx.x + gx * (blockIdx.y + gy * blockIdx.z);
    const int cpx = (gx * gy * (int)gridDim.z) >> 3;
    lin = (lin & 7) * cpx + (lin >> 3);
    const int bx = lin % gx; const int rest = lin / gx;
    const int by = rest % gy, bz = rest / gy;

    const long long m0 = (long long)bx * 256;
    const long long n0 = (long long)by * 256;
    const int KC = K / gridDim.z;
    const int kbase = bz * KC;
    const int wm = (wv >> 2) * 128, wn = (wv & 3) * 64;
    const int fr = lane & 15, fq = lane >> 4;

    // staging: 1024 16B-slots per matrix tile; thread covers slots tid, tid+512.
    // phys slot (L,p) <- global row L+128*(p'>>2), k-group p'&3, p' = p^(L&7).
    const int sI0 = tid, sI1 = tid + 512;
    const int L0 = sI0 >> 3, p0 = (sI0 & 7) ^ (L0 & 7);
    const int L1 = sI1 >> 3, p1 = (sI1 & 7) ^ (L1 & 7);
    const int row0 = L0 + ((p0 >> 2) << 7), kg0 = (p0 & 3) << 3;
    const int row1 = L1 + ((p1 >> 2) << 7), kg1 = (p1 & 3) << 3;
    const _Float16* sA0 = A + (m0 + row0) * (long long)lda + kbase + kg0;
    const _Float16* sA1 = A + (m0 + row1) * (long long)lda + kbase + kg1;
    const _Float16* sB0 = B + (n0 + row0) * (long long)ldb + kbase + kg0;
    const _Float16* sB1 = B + (n0 + row1) * (long long)ldb + kbase + kg1;
    const int dst0 = (wv * 64) * 8;          // halfs; lane adds 16B
    const int dst1 = (512 + wv * 64) * 8;

    f32x4 acc[8][4] = {};
    const int NT = KC / 32;

#define STAGE(kt3)                                                        \
    if ((kt3) < NT) {                                                     \
        const int bb_ = (kt3) & 3;                                        \
        const long long ko_ = (long long)(kt3) * 32;                      \
        gl_lds16(sA0 + ko_, &Ah[bb_][dst0]);                              \
        gl_lds16(sB0 + ko_, &Bh[bb_][dst0]);                              \
        gl_lds16(sA1 + ko_, &Ah[bb_][dst1]);                              \
        gl_lds16(sB1 + ko_, &Bh[bb_][dst1]);                              \
    }

    STAGE(0); STAGE(1); STAGE(2);

    const int abit = (wm >> 7) << 2;         // wave-uniform col-half selector
    for (int kt = 0; kt < NT; ++kt) {
        if (kt + 2 < NT)      asm volatile("s_waitcnt vmcnt(8)" ::: "memory");
        else if (kt + 1 < NT) asm volatile("s_waitcnt vmcnt(4)" ::: "memory");
        else                  asm volatile("s_waitcnt vmcnt(0)" ::: "memory");
        __builtin_amdgcn_s_barrier();
        STAGE(kt + 3);

        const int bb = kt & 3;
        hlf8 a[8], b[4];
#pragma unroll
        for (int i = 0; i < 8; ++i) {
            const int rr = wm + i * 16 + fr;
            const int L = rr & 127;
            const int ph = (abit | fq) ^ (L & 7);
            a[i] = *(const hlf8*)&Ah[bb][L * 64 + ph * 8];
        }
#pragma unroll
        for (int j = 0; j < 4; ++j) {
            const int cc = wn + j * 16 + fr;
            const int L = cc & 127;
            const int ph = ((((cc >> 7) << 2)) | fq) ^ (L & 7);
            b[j] = *(const hlf8*)&Bh[bb][L * 64 + ph * 8];
        }
        __builtin_amdgcn_s_setprio(1);
#pragma unroll
        for (int i = 0; i < 8; ++i)
#pragma unroll
            for (int j = 0; j < 4; ++j)
                acc[i][j] = __builtin_amdgcn_mfma_f32_16x16x32_f16(a[i], b[j], acc[i][j], 0, 0, 0);
        __builtin_amdgcn_s_setprio(0);
    }
#undef STAGE

    // C/D layout: col=lane&15, row=(lane>>4)*4+reg (m89-verified)
    if constexpr (OUT16) {
        _Float16* op = (_Float16*)Cc;
#pragma unroll
        for (int i = 0; i < 8; ++i)
#pragma unroll
            for (int j = 0; j < 4; ++j) {
                _Float16* cp = op + (m0 + wm + i * 16 + fq * 4) * ldc + (n0 + wn + j * 16 + fr);
#pragma unroll
                for (int r = 0; r < 4; ++r) cp[(long long)r * ldc] = (_Float16)acc[i][j][r];
            }
    } else {
        float* outp = (gridDim.z == 1) ? (float*)Cc : (part + (long long)bz * zstride);
#pragma unroll
        for (int i = 0; i < 8; ++i)
#pragma unroll
            for (int j = 0; j < 4; ++j) {
                float* cp = outp + (m0 + wm + i * 16 + fq * 4) * ldc + (n0 + wn + j * 16 + fr);
#pragma unroll
                for (int r = 0; r < 4; ++r) cp[(long long)r * ldc] = acc[i][j][r];
            }
    }
}

// ---------------- split-K reduction: out = sum_z part[z] ----------------
__global__ __launch_bounds__(256) void k_redux(
    const float* __restrict__ part, float* __restrict__ out,
    long long n4, long long zs4, int Z) {
    long long i = blockIdx.x * 256ll + threadIdx.x;
    long long stride = (long long)gridDim.x * 256ll;
    for (; i < n4; i += stride) {
        float4 s = ((const float4*)part)[i];
        for (int z = 1; z < Z; ++z) {
            float4 t = ((const float4*)part)[i + z * zs4];
            s.x += t.x; s.y += t.y; s.z += t.z; s.w += t.w;
        }
        ((float4*)out)[i] = s;
    }
}

// ---------------- row LayerNorm in-place, width W = CNT*256 ----------------
template <int CNT>
__global__ __launch_bounds__(256) void k_layernorm(
    float* __restrict__ Y, const float* __restrict__ g,
    const float* __restrict__ b, int W) {
    float* yr = Y + (long long)blockIdx.x * W;
    float v[CNT];
    float s = 0.f;
#pragma unroll
    for (int i = 0; i < CNT; ++i) {
        v[i] = yr[threadIdx.x + (i << 8)];
        s += v[i];
    }
    float mu = blk_sum(s) / (float)W;
    float sq = 0.f;
#pragma unroll
    for (int i = 0; i < CNT; ++i) {
        float d = v[i] - mu;
        sq = fmaf(d, d, sq);
    }
    float var = blk_sum(sq) / (float)W;
    float rs = rsqrtf(var + 1e-5f);
#pragma unroll
    for (int i = 0; i < CNT; ++i) {
        int col = threadIdx.x + (i << 8);
        yr[col] = (v[i] - mu) * rs * g[col] + b[col];
    }
}

// -------- softmax over f16 pre-scaled logits, W = 16384 ---------------------
__global__ __launch_bounds__(256) void k_softmax_h(
    _Float16* __restrict__ Sh, float* __restrict__ attnf) {
    _Float16* sr = Sh + (long long)blockIdx.x * 16384;
    float* ar = attnf + (long long)blockIdx.x * 16384;
    float4 r[16];
    float mx = -1e30f;
#pragma unroll
    for (int i = 0; i < 16; ++i) {
        hlf4 h = ((const hlf4*)sr)[threadIdx.x + (i << 8)];
        float4 t = {(float)h[0], (float)h[1], (float)h[2], (float)h[3]};
        r[i] = t;
        mx = fmaxf(mx, fmaxf(fmaxf(t.x, t.y), fmaxf(t.z, t.w)));
    }
    mx = blk_max(mx);
    float sum = 0.f;
#pragma unroll
    for (int i = 0; i < 16; ++i) {
        float4 t = r[i];
        t.x = __expf(t.x - mx); t.y = __expf(t.y - mx);
        t.z = __expf(t.z - mx); t.w = __expf(t.w - mx);
        r[i] = t;
        sum += t.x + t.y + t.z + t.w;
    }
    sum = blk_sum(sum);
    float inv = 1.0f / sum;
#pragma unroll
    for (int i = 0; i < 16; ++i) {
        float4 t = r[i];
        t.x *= inv; t.y *= inv; t.z *= inv; t.w *= inv;
        ((float4*)ar)[threadIdx.x + (i << 8)] = t;
        hlf4 o = {(_Float16)t.x, (_Float16)t.y, (_Float16)t.z, (_Float16)t.w};
        ((hlf4*)sr)[threadIdx.x + (i << 8)] = o;
    }
}

// -------- legacy f32-logits softmax (fallback path only) --------------------
__global__ __launch_bounds__(256) void k_softmax(
    float* __restrict__ S, _Float16* __restrict__ Sh, float scale) {
    float* sr = S + (long long)blockIdx.x * 16384;
    _Float16* shr = Sh ? Sh + (long long)blockIdx.x * 16384 : nullptr;
    float4 r[16];
    float mx = -1e30f;
#pragma unroll
    for (int i = 0; i < 16; ++i) {
        float4 t = ((const float4*)sr)[threadIdx.x + (i << 8)];
        t.x *= scale; t.y *= scale; t.z *= scale; t.w *= scale;
        r[i] = t;
        mx = fmaxf(mx, fmaxf(fmaxf(t.x, t.y), fmaxf(t.z, t.w)));
    }
    mx = blk_max(mx);
    float sum = 0.f;
#pragma unroll
    for (int i = 0; i < 16; ++i) {
        float4 t = r[i];
        t.x = __expf(t.x - mx); t.y = __expf(t.y - mx);
        t.z = __expf(t.z - mx); t.w = __expf(t.w - mx);
        r[i] = t;
        sum += t.x + t.y + t.z + t.w;
    }
    sum = blk_sum(sum);
    float inv = 1.0f / sum;
#pragma unroll
    for (int i = 0; i < 16; ++i) {
        float4 t = r[i];
        t.x *= inv; t.y *= inv; t.z *= inv; t.w *= inv;
        ((float4*)sr)[threadIdx.x + (i << 8)] = t;
        if (shr) {
            hlf4 o = {(_Float16)t.x, (_Float16)t.y, (_Float16)t.z, (_Float16)t.w};
            ((hlf4*)shr)[threadIdx.x + (i << 8)] = o;
        }
    }
}

extern "C" void kernel_launch(void* const* d_in, const int* in_sizes, int n_in,
                              void* d_out, int out_size, void* d_ws, size_t ws_size,
                              hipStream_t stream) {
    const float* x      = (const float*)d_in[0];
    const float* X_data = (const float*)d_in[1];
    const int*   midx   = (const int*)d_in[2];
    const float* W_q    = (const float*)d_in[3];
    const float* W_k    = (const float*)d_in[4];
    const float* W_v    = (const float*)d_in[5];
    const float* g_q    = (const float*)d_in[6];
    const float* b_q    = (const float*)d_in[7];
    const float* g_k    = (const float*)d_in[8];
    const float* b_k    = (const float*)d_in[9];
    const float* g_v    = (const float*)d_in[10];
    const float* b_v    = (const float*)d_in[11];

    const int n  = in_sizes[10];        // 1024
    const int a  = in_sizes[6];         // 256
    const int m  = in_sizes[2];         // 16384
    const int Bn = in_sizes[0] / n;     // 4096

    // output layout: xs | x_hat | attn | v
    float* out  = (float*)d_out;
    float* xs   = out;
    float* xhat = xs + (long long)Bn * n;
    float* attn = xhat + (long long)Bn * n;
    float* vout = attn + (long long)Bn * m;

    // workspace carving (256B aligned). [qmat .. k_h] (~73 MB) is dead before
    // the x_hat GEMM, so the 64 MB split-K partial buffer aliases it.
    char* wp = (char*)d_ws;
    auto carve = [&](size_t bytes) -> char* {
        char* r = wp; wp += (bytes + 255) & ~(size_t)255; return r;
    };
    float*     norms = (float*)carve((size_t)m * 4);
    float*     cinv  = (float*)carve(16);
    char*      alias0 = wp;
    float*     qmat  = (float*)carve((size_t)Bn * a * 4);
    float*     kmat  = (float*)carve((size_t)m * a * 4);
    _Float16*  xs_h  = (_Float16*)carve((size_t)Bn * n * 2);
    _Float16*  Xc_h  = (_Float16*)carve((size_t)m * n * 2);
    _Float16*  Wq_h  = (_Float16*)carve((size_t)a * n * 2);
    _Float16*  Wk_h  = (_Float16*)carve((size_t)a * n * 2);
    _Float16*  Wv_h  = (_Float16*)carve((size_t)n * n * 2);
    _Float16*  q_h   = (_Float16*)carve((size_t)Bn * a * 2);
    _Float16*  k_h   = (_Float16*)carve((size_t)m * a * 2);
    float*     splitk = (float*)alias0;
    const int  SK = 4;                                    // SK*Bn*n*4 = 64MB <= 73MB
    _Float16*  vT_h  = (_Float16*)carve((size_t)n * m * 2);
    size_t used = (size_t)(wp - (char*)d_ws);
    _Float16* attn_h = nullptr;
    if (ws_size >= used + (size_t)Bn * m * 2 + 256)
        attn_h = (_Float16*)carve((size_t)Bn * m * 2);

    // 1) gather (C-free now) + C normalizer in parallel
    hipLaunchKernelGGL(k_gather_cvt, dim3(m), dim3(256), 0, stream,
                       X_data, midx, Xc_h, n);
    hipLaunchKernelGGL(k_row_norms, dim3(m), dim3(256), 0, stream, X_data, midx, norms, n);
    hipLaunchKernelGGL(k_cinv, dim3(1), dim3(256), 0, stream, norms, m, n, cinv);

    // 2) xs = x/C (f32 output) + unscaled f16 copy for q projection
    hipLaunchKernelGGL(k_scale2, dim3(2048), dim3(256), 0, stream,
                       x, cinv, xs, xs_h, (long long)Bn * n / 4);

    // 3) weights -> f16
    hipLaunchKernelGGL(k_cvt, dim3(256), dim3(256), 0, stream, W_q, Wq_h, (long long)a * n / 4, 1.f);
    hipLaunchKernelGGL(k_cvt, dim3(256), dim3(256), 0, stream, W_k, Wk_h, (long long)a * n / 4, 1.f);
    hipLaunchKernelGGL(k_cvt, dim3(1024), dim3(256), 0, stream, W_v, Wv_h, (long long)n * n / 4, 1.f);

    // 4) projections: q,k on 128² m97 kernel; v on ring-4 256²
    hipLaunchKernelGGL(k_gemm4, dim3(Bn / 128, a / 128), dim3(256), 0, stream,
                       xs_h, n, Wq_h, n, qmat, a, n, (float*)nullptr, 0ll);
    hipLaunchKernelGGL(k_gemm4, dim3(m / 128, a / 128), dim3(256), 0, stream,
                       Xc_h, n, Wk_h, n, kmat, a, n, (float*)nullptr, 0ll);
    hipLaunchKernelGGL((k_g256<0>), dim3(m / 256, n / 256), dim3(512), 0, stream,
                       Xc_h, n, Wv_h, n, vout, n, n, (float*)nullptr, 0ll);

    // 5) LayerNorms (f32); f16 copies: q scaled by 1/sqrt(a), k plain, v transposed
    float sc = 1.0f / sqrtf((float)a);
    hipLaunchKernelGGL(k_layernorm<1>, dim3(Bn), dim3(256), 0, stream, qmat, g_q, b_q, a);
    hipLaunchKernelGGL(k_layernorm<1>, dim3(m),  dim3(256), 0, stream, kmat, g_k, b_k, a);
    hipLaunchKernelGGL(k_layernorm<4>, dim3(m),  dim3(256), 0, stream, vout, g_v, b_v, n);
    hipLaunchKernelGGL(k_cvt, dim3(1024), dim3(256), 0, stream, qmat, q_h, (long long)Bn * a / 4, sc);
    hipLaunchKernelGGL(k_cvt, dim3(4096), dim3(256), 0, stream, kmat, k_h, (long long)m * a / 4, 1.f);
    hipLaunchKernelGGL(k_tcvt, dim3(n / 32, m / 32), dim3(256), 0, stream, vout, vT_h, m, n);

    long long zstride = (long long)Bn * n;
    if (attn_h) {
        // 6) S (pre-scaled, f16) -> attn_h; softmax reads f16, writes f32 + f16
        hipLaunchKernelGGL((k_g256<1>), dim3(Bn / 256, m / 256), dim3(512), 0, stream,
                           q_h, a, k_h, a, attn_h, m, a, (float*)nullptr, 0ll);
        hipLaunchKernelGGL(k_softmax_h, dim3(Bn), dim3(256), 0, stream, attn_h, attn);
        // 7) x_hat = attn @ v, split-K=4 into aliased partials, then reduce
        hipLaunchKernelGGL((k_g256<0>), dim3(Bn / 256, n / 256, SK), dim3(512), 0, stream,
                           attn_h, m, vT_h, m, xhat, n, m, splitk, zstride);
        hipLaunchKernelGGL(k_redux, dim3(2048), dim3(256), 0, stream,
                           splitk, xhat, (long long)Bn * n / 4, zstride / 4, SK);
    } else {
        // fallback (never exercised): f32 logits + legacy softmax + chunked cvt/GEMM
        hipLaunchKernelGGL((k_g256<0>), dim3(Bn / 256, m / 256), dim3(512), 0, stream,
                           q_h, a, k_h, a, attn, m, a, (float*)nullptr, 0ll);
        hipLaunchKernelGGL(k_softmax, dim3(Bn), dim3(256), 0, stream, attn, (_Float16*)nullptr, 1.0f);
        _Float16* chunk_h = (_Float16*)splitk;           // 1024*16384*2 = 32MB
        for (int cb = 0; cb < 4; ++cb) {
            const float* src = attn + (long long)cb * 1024 * m;
            hipLaunchKernelGGL(k_cvt, dim3(4096), dim3(256), 0, stream,
                               src, chunk_h, (long long)1024 * m / 4, 1.f);
            hipLaunchKernelGGL((k_g256<0>), dim3(1024 / 256, n / 256), dim3(512), 0, stream,
                               chunk_h, m, vT_h, m, xhat + (long long)cb * 1024 * n, n, m,
                               (float*)nullptr, 0ll);
        }
    }
}

// Round 9
// 570.557 us; speedup vs baseline: 1.1869x; 1.1869x over previous
//
#include <hip/hip_runtime.h>
#include <math.h>

typedef _Float16 hlf4 __attribute__((ext_vector_type(4)));
typedef _Float16 hlf8 __attribute__((ext_vector_type(8)));
typedef float f32x4 __attribute__((ext_vector_type(4)));

// async global->LDS, 16B per lane; lds base must be wave-uniform
static __device__ __forceinline__ void gl_lds16(const void* g, void* l) {
    __builtin_amdgcn_global_load_lds(
        (const __attribute__((address_space(1))) unsigned int*)g,
        (__attribute__((address_space(3))) unsigned int*)l, 16, 0, 0);
}

// ---------------- block reductions (deterministic tree order) ----------------
static __device__ __forceinline__ float blk_sum(float v) {
    __shared__ float sm[256];
    int tid = threadIdx.x;
    sm[tid] = v; __syncthreads();
#pragma unroll
    for (int s = 128; s > 0; s >>= 1) {
        if (tid < s) sm[tid] += sm[tid + s];
        __syncthreads();
    }
    float r = sm[0]; __syncthreads();
    return r;
}

static __device__ __forceinline__ float blk_max(float v) {
    __shared__ float sm[256];
    int tid = threadIdx.x;
    sm[tid] = v; __syncthreads();
#pragma unroll
    for (int s = 128; s > 0; s >>= 1) {
        if (tid < s) sm[tid] = fmaxf(sm[tid], sm[tid + s]);
        __syncthreads();
    }
    float r = sm[0]; __syncthreads();
    return r;
}

// ---------------- C normalizer: per-row norms of gathered rows ----------------
__global__ __launch_bounds__(256) void k_row_norms(
    const float* __restrict__ X, const int* __restrict__ idx,
    float* __restrict__ norms, int n) {
    long long r = idx[blockIdx.x];
    const float* xr = X + r * (long long)n;
    float s = 0.f;
    for (int k = threadIdx.x * 4; k < n; k += 256 * 4) {
        float4 v = *(const float4*)(xr + k);
        s = fmaf(v.x, v.x, s); s = fmaf(v.y, v.y, s);
        s = fmaf(v.z, v.z, s); s = fmaf(v.w, v.w, s);
    }
    float tot = blk_sum(s);
    if (threadIdx.x == 0) norms[blockIdx.x] = sqrtf(tot);
}

__global__ __launch_bounds__(256) void k_cinv(
    const float* __restrict__ norms, int m, int n, float* __restrict__ cinv) {
    float s = 0.f;
    for (int i = threadIdx.x; i < m; i += 256) s += norms[i];
    float tot = blk_sum(s);
    if (threadIdx.x == 0) cinv[0] = (float)m * sqrtf((float)n) / tot;  // 1/C
}

// ------- xs = x * (1/C) f32 (output) + UNSCALED f16 copy (LN-invariant) -----
__global__ __launch_bounds__(256) void k_scale2(
    const float* __restrict__ x, const float* __restrict__ cinv,
    float* __restrict__ y, _Float16* __restrict__ yh, long long total4) {
    float c = cinv[0];
    long long i = blockIdx.x * 256ll + threadIdx.x;
    long long stride = (long long)gridDim.x * 256ll;
    for (; i < total4; i += stride) {
        float4 v = ((const float4*)x)[i];
        float4 w = {v.x * c, v.y * c, v.z * c, v.w * c};
        ((float4*)y)[i] = w;
        // q = LN(xs@Wq^T) is invariant to the 1/C scale -> unscaled f16 copy
        hlf4 o = {(_Float16)v.x, (_Float16)v.y, (_Float16)v.z, (_Float16)v.w};
        ((hlf4*)yh)[i] = o;
    }
}

// -------- gather + cvt (NO 1/C scale: k,v are LN-invariant to it) -----------
__global__ __launch_bounds__(256) void k_gather_cvt(
    const float* __restrict__ X, const int* __restrict__ idx,
    _Float16* __restrict__ out, int n) {
    long long r = idx[blockIdx.x];
    const float* src = X + r * (long long)n;
    _Float16* dst = out + (long long)blockIdx.x * n;
    for (int k = threadIdx.x * 4; k < n; k += 256 * 4) {
        float4 v = *(const float4*)(src + k);
        hlf4 o = {(_Float16)v.x, (_Float16)v.y, (_Float16)v.z, (_Float16)v.w};
        *(hlf4*)(dst + k) = o;
    }
}

// ---------------- flat f32 -> f16 with scalar scale ----------------
__global__ __launch_bounds__(256) void k_cvt(
    const float* __restrict__ in, _Float16* __restrict__ out, long long n4,
    float sc) {
    long long i = blockIdx.x * 256ll + threadIdx.x;
    long long stride = (long long)gridDim.x * 256ll;
    for (; i < n4; i += stride) {
        float4 v = ((const float4*)in)[i];
        hlf4 o = {(_Float16)(v.x * sc), (_Float16)(v.y * sc),
                  (_Float16)(v.z * sc), (_Float16)(v.w * sc)};
        ((hlf4*)out)[i] = o;
    }
}

// ---------------- transpose + cvt: in[R][Cc] f32 -> out[Cc][R] f16 ----------
__global__ __launch_bounds__(256) void k_tcvt(
    const float* __restrict__ in, _Float16* __restrict__ out, int R, int Cc) {
    __shared__ _Float16 t[32][34];
    int tx = threadIdx.x & 31, ty = threadIdx.x >> 5;   // ty 0..7
    int c0 = blockIdx.x * 32, r0 = blockIdx.y * 32;
#pragma unroll
    for (int i = 0; i < 32; i += 8)
        t[ty + i][tx] = (_Float16)in[(long long)(r0 + ty + i) * Cc + c0 + tx];
    __syncthreads();
#pragma unroll
    for (int i = 0; i < 32; i += 8)
        out[(long long)(c0 + ty + i) * R + r0 + tx] = t[tx][ty + i];
}

// ================= m97-structure MFMA NT GEMM (128² tile, 4 waves) ==========
// Proven R4 kernel (215 µs x_hat, MfmaUtil 27%, HBM-bound). MODE:
//   0 = f32 C (direct or split-K partial)
//   1 = f16 exp(C - 5) — logits-with-exp epilogue (fixed shift; |S|<=16 by
//       Cauchy-Schwarz on LN'd rows * 1/sqrt(a); e^11 < f16 max)
template <int MODE>
__global__ __launch_bounds__(256) void k_gemm4(
    const _Float16* __restrict__ A, int lda,
    const _Float16* __restrict__ B, int ldb,
    void* __restrict__ Cc, long long ldc, int K,
    float* __restrict__ part, long long zstride) {
    __shared__ _Float16 Ah[2][4096];
    __shared__ _Float16 Bh[2][4096];
    const int tid = threadIdx.x;
    const long long m0 = (long long)blockIdx.x * 128;
    const long long n0 = (long long)blockIdx.y * 128;
    const int KC = K / gridDim.z;
    const int kbase = blockIdx.z * KC;
    const int lane = tid & 63, wv = tid >> 6;
    const int wm = (wv >> 1) * 64, wn = (wv & 1) * 64;
    const int fr = lane & 15, fq = lane >> 4;

    const int s0 = tid, s1 = tid + 256;
    const int r0s = s0 >> 2, r1s = s1 >> 2;
    const int g0 = (((s0 & 3) ^ (r0s & 3)) << 3);
    const int g1 = (((s1 & 3) ^ (r1s & 3)) << 3);
    const _Float16* A0 = A + (m0 + r0s) * (long long)lda + kbase + g0;
    const _Float16* A1 = A + (m0 + r1s) * (long long)lda + kbase + g1;
    const _Float16* B0 = B + (n0 + r0s) * (long long)ldb + kbase + g0;
    const _Float16* B1 = B + (n0 + r1s) * (long long)ldb + kbase + g1;

    f32x4 acc[4][4] = {};

    const int NT = KC / 32;
    {
        gl_lds16(A0, &Ah[0][wv * 512]);
        gl_lds16(A1, &Ah[0][2048 + wv * 512]);
        gl_lds16(B0, &Bh[0][wv * 512]);
        gl_lds16(B1, &Bh[0][2048 + wv * 512]);
    }
    __syncthreads();

    for (int kt = 0; kt < NT; ++kt) {
        const int cur = kt & 1;
        if (kt + 1 < NT) {
            const int nx = cur ^ 1;
            const long long ko = (long long)(kt + 1) * 32;
            gl_lds16(A0 + ko, &Ah[nx][wv * 512]);
            gl_lds16(A1 + ko, &Ah[nx][2048 + wv * 512]);
            gl_lds16(B0 + ko, &Bh[nx][wv * 512]);
            gl_lds16(B1 + ko, &Bh[nx][2048 + wv * 512]);
        }
        hlf8 af[4], bf[4];
#pragma unroll
        for (int i = 0; i < 4; ++i) {
            const int r = wm + i * 16 + fr;
            af[i] = *(const hlf8*)&Ah[cur][r * 32 + ((fq ^ (r & 3)) << 3)];
        }
#pragma unroll
        for (int j = 0; j < 4; ++j) {
            const int r = wn + j * 16 + fr;
            bf[j] = *(const hlf8*)&Bh[cur][r * 32 + ((fq ^ (r & 3)) << 3)];
        }
#pragma unroll
        for (int i = 0; i < 4; ++i)
#pragma unroll
            for (int j = 0; j < 4; ++j)
                acc[i][j] = __builtin_amdgcn_mfma_f32_16x16x32_f16(af[i], bf[j], acc[i][j], 0, 0, 0);
        __syncthreads();
    }

    // C/D layout: col=lane&15, row=(lane>>4)*4+reg (m89-verified)
    if constexpr (MODE == 1) {
        _Float16* op = (_Float16*)Cc;
#pragma unroll
        for (int i = 0; i < 4; ++i)
#pragma unroll
            for (int j = 0; j < 4; ++j) {
                _Float16* cp = op + (m0 + wm + i * 16 + fq * 4) * ldc + (n0 + wn + j * 16 + fr);
#pragma unroll
                for (int r = 0; r < 4; ++r)
                    cp[(long long)r * ldc] = (_Float16)__expf(acc[i][j][r] - 5.0f);
            }
    } else {
        float* outp = (gridDim.z == 1) ? (float*)Cc : (part + (long long)blockIdx.z * zstride);
#pragma unroll
        for (int i = 0; i < 4; ++i)
#pragma unroll
            for (int j = 0; j < 4; ++j) {
                float* cp = outp + (m0 + wm + i * 16 + fq * 4) * ldc + (n0 + wn + j * 16 + fr);
#pragma unroll
                for (int r = 0; r < 4; ++r) cp[(long long)r * ldc] = acc[i][j][r];
            }
    }
}

// ------- split-K reduction with optional per-row scale: out = inv[row]*Σ ----
__global__ __launch_bounds__(256) void k_redux(
    const float* __restrict__ part, float* __restrict__ out,
    long long n4, long long zs4, int Z,
    const float* __restrict__ invs, int rowdiv4) {
    long long i = blockIdx.x * 256ll + threadIdx.x;
    long long stride = (long long)gridDim.x * 256ll;
    for (; i < n4; i += stride) {
        float4 s = ((const float4*)part)[i];
        for (int z = 1; z < Z; ++z) {
            float4 t = ((const float4*)part)[i + z * zs4];
            s.x += t.x; s.y += t.y; s.z += t.z; s.w += t.w;
        }
        if (invs) {
            float iv = invs[i / rowdiv4];
            s.x *= iv; s.y *= iv; s.z *= iv; s.w *= iv;
        }
        ((float4*)out)[i] = s;
    }
}

// ---------------- row LayerNorm in-place, width W = CNT*256 ----------------
template <int CNT>
__global__ __launch_bounds__(256) void k_layernorm(
    float* __restrict__ Y, const float* __restrict__ g,
    const float* __restrict__ b, int W) {
    float* yr = Y + (long long)blockIdx.x * W;
    float v[CNT];
    float s = 0.f;
#pragma unroll
    for (int i = 0; i < CNT; ++i) {
        v[i] = yr[threadIdx.x + (i << 8)];
        s += v[i];
    }
    float mu = blk_sum(s) / (float)W;
    float sq = 0.f;
#pragma unroll
    for (int i = 0; i < CNT; ++i) {
        float d = v[i] - mu;
        sq = fmaf(d, d, sq);
    }
    float var = blk_sum(sq) / (float)W;
    float rs = rsqrtf(var + 1e-5f);
#pragma unroll
    for (int i = 0; i < CNT; ++i) {
        int col = threadIdx.x + (i << 8);
        yr[col] = (v[i] - mu) * rs * g[col] + b[col];
    }
}

// -------- sum-only softmax over E = exp(S-5) f16, W = 16384 -----------------
// writes attn = E*inv (f32) and invs[row] = 1/sum for the x_hat epilogue.
__global__ __launch_bounds__(256) void k_softmax_e(
    const _Float16* __restrict__ E, float* __restrict__ attnf,
    float* __restrict__ invs) {
    const _Float16* er = E + (long long)blockIdx.x * 16384;
    float* ar = attnf + (long long)blockIdx.x * 16384;
    float4 r[16];
    float sum = 0.f;
#pragma unroll
    for (int i = 0; i < 16; ++i) {
        hlf4 h = ((const hlf4*)er)[threadIdx.x + (i << 8)];
        float4 t = {(float)h[0], (float)h[1], (float)h[2], (float)h[3]};
        r[i] = t;
        sum += t.x + t.y + t.z + t.w;
    }
    sum = blk_sum(sum);
    float inv = 1.0f / sum;
    if (threadIdx.x == 0) invs[blockIdx.x] = inv;
#pragma unroll
    for (int i = 0; i < 16; ++i) {
        float4 t = r[i];
        t.x *= inv; t.y *= inv; t.z *= inv; t.w *= inv;
        ((float4*)ar)[threadIdx.x + (i << 8)] = t;
    }
}

// -------- legacy f32-logits softmax (fallback path only) --------------------
__global__ __launch_bounds__(256) void k_softmax(
    float* __restrict__ S, _Float16* __restrict__ Sh, float scale) {
    float* sr = S + (long long)blockIdx.x * 16384;
    _Float16* shr = Sh ? Sh + (long long)blockIdx.x * 16384 : nullptr;
    float4 r[16];
    float mx = -1e30f;
#pragma unroll
    for (int i = 0; i < 16; ++i) {
        float4 t = ((const float4*)sr)[threadIdx.x + (i << 8)];
        t.x *= scale; t.y *= scale; t.z *= scale; t.w *= scale;
        r[i] = t;
        mx = fmaxf(mx, fmaxf(fmaxf(t.x, t.y), fmaxf(t.z, t.w)));
    }
    mx = blk_max(mx);
    float sum = 0.f;
#pragma unroll
    for (int i = 0; i < 16; ++i) {
        float4 t = r[i];
        t.x = __expf(t.x - mx); t.y = __expf(t.y - mx);
        t.z = __expf(t.z - mx); t.w = __expf(t.w - mx);
        r[i] = t;
        sum += t.x + t.y + t.z + t.w;
    }
    sum = blk_sum(sum);
    float inv = 1.0f / sum;
#pragma unroll
    for (int i = 0; i < 16; ++i) {
        float4 t = r[i];
        t.x *= inv; t.y *= inv; t.z *= inv; t.w *= inv;
        ((float4*)sr)[threadIdx.x + (i << 8)] = t;
        if (shr) {
            hlf4 o = {(_Float16)t.x, (_Float16)t.y, (_Float16)t.z, (_Float16)t.w};
            ((hlf4*)shr)[threadIdx.x + (i << 8)] = o;
        }
    }
}

extern "C" void kernel_launch(void* const* d_in, const int* in_sizes, int n_in,
                              void* d_out, int out_size, void* d_ws, size_t ws_size,
                              hipStream_t stream) {
    const float* x      = (const float*)d_in[0];
    const float* X_data = (const float*)d_in[1];
    const int*   midx   = (const int*)d_in[2];
    const float* W_q    = (const float*)d_in[3];
    const float* W_k    = (const float*)d_in[4];
    const float* W_v    = (const float*)d_in[5];
    const float* g_q    = (const float*)d_in[6];
    const float* b_q    = (const float*)d_in[7];
    const float* g_k    = (const float*)d_in[8];
    const float* b_k    = (const float*)d_in[9];
    const float* g_v    = (const float*)d_in[10];
    const float* b_v    = (const float*)d_in[11];

    const int n  = in_sizes[10];        // 1024
    const int a  = in_sizes[6];         // 256
    const int m  = in_sizes[2];         // 16384
    const int Bn = in_sizes[0] / n;     // 4096

    // output layout: xs | x_hat | attn | v
    float* out  = (float*)d_out;
    float* xs   = out;
    float* xhat = xs + (long long)Bn * n;
    float* attn = xhat + (long long)Bn * n;
    float* vout = attn + (long long)Bn * m;

    // workspace carving (256B aligned). [qmat .. k_h] (~73 MB) is dead before
    // the x_hat GEMM, so the 64 MB split-K partial buffer aliases it.
    // invs must live OUTSIDE the aliased span (read after partials written).
    char* wp = (char*)d_ws;
    auto carve = [&](size_t bytes) -> char* {
        char* r = wp; wp += (bytes + 255) & ~(size_t)255; return r;
    };
    float*     norms = (float*)carve((size_t)m * 4);
    float*     cinv  = (float*)carve(16);
    float*     invs  = (float*)carve((size_t)Bn * 4);
    char*      alias0 = wp;
    float*     qmat  = (float*)carve((size_t)Bn * a * 4);
    float*     kmat  = (float*)carve((size_t)m * a * 4);
    _Float16*  xs_h  = (_Float16*)carve((size_t)Bn * n * 2);
    _Float16*  Xc_h  = (_Float16*)carve((size_t)m * n * 2);
    _Float16*  Wq_h  = (_Float16*)carve((size_t)a * n * 2);
    _Float16*  Wk_h  = (_Float16*)carve((size_t)a * n * 2);
    _Float16*  Wv_h  = (_Float16*)carve((size_t)n * n * 2);
    _Float16*  q_h   = (_Float16*)carve((size_t)Bn * a * 2);
    _Float16*  k_h   = (_Float16*)carve((size_t)m * a * 2);
    float*     splitk = (float*)alias0;
    const int  SK = 4;                                    // SK*Bn*n*4 = 64MB <= 73MB
    _Float16*  vT_h  = (_Float16*)carve((size_t)n * m * 2);
    size_t used = (size_t)(wp - (char*)d_ws);
    _Float16* attn_h = nullptr;
    if (ws_size >= used + (size_t)Bn * m * 2 + 256)
        attn_h = (_Float16*)carve((size_t)Bn * m * 2);

    // 1) gather (C-free) + C normalizer in parallel
    hipLaunchKernelGGL(k_gather_cvt, dim3(m), dim3(256), 0, stream,
                       X_data, midx, Xc_h, n);
    hipLaunchKernelGGL(k_row_norms, dim3(m), dim3(256), 0, stream, X_data, midx, norms, n);
    hipLaunchKernelGGL(k_cinv, dim3(1), dim3(256), 0, stream, norms, m, n, cinv);

    // 2) xs = x/C (f32 output) + unscaled f16 copy for q projection
    hipLaunchKernelGGL(k_scale2, dim3(2048), dim3(256), 0, stream,
                       x, cinv, xs, xs_h, (long long)Bn * n / 4);

    // 3) weights -> f16
    hipLaunchKernelGGL(k_cvt, dim3(256), dim3(256), 0, stream, W_q, Wq_h, (long long)a * n / 4, 1.f);
    hipLaunchKernelGGL(k_cvt, dim3(256), dim3(256), 0, stream, W_k, Wk_h, (long long)a * n / 4, 1.f);
    hipLaunchKernelGGL(k_cvt, dim3(1024), dim3(256), 0, stream, W_v, Wv_h, (long long)n * n / 4, 1.f);

    // 4) projections (all on proven 128² kernel)
    hipLaunchKernelGGL((k_gemm4<0>), dim3(Bn / 128, a / 128), dim3(256), 0, stream,
                       xs_h, n, Wq_h, n, qmat, a, n, (float*)nullptr, 0ll);
    hipLaunchKernelGGL((k_gemm4<0>), dim3(m / 128, a / 128), dim3(256), 0, stream,
                       Xc_h, n, Wk_h, n, kmat, a, n, (float*)nullptr, 0ll);
    hipLaunchKernelGGL((k_gemm4<0>), dim3(m / 128, n / 128), dim3(256), 0, stream,
                       Xc_h, n, Wv_h, n, vout, n, n, (float*)nullptr, 0ll);

    // 5) LayerNorms (f32); f16 copies: q scaled by 1/sqrt(a), k plain, v transposed
    float sc = 1.0f / sqrtf((float)a);
    hipLaunchKernelGGL(k_layernorm<1>, dim3(Bn), dim3(256), 0, stream, qmat, g_q, b_q, a);
    hipLaunchKernelGGL(k_layernorm<1>, dim3(m),  dim3(256), 0, stream, kmat, g_k, b_k, a);
    hipLaunchKernelGGL(k_layernorm<4>, dim3(m),  dim3(256), 0, stream, vout, g_v, b_v, n);
    hipLaunchKernelGGL(k_cvt, dim3(1024), dim3(256), 0, stream, qmat, q_h, (long long)Bn * a / 4, sc);
    hipLaunchKernelGGL(k_cvt, dim3(4096), dim3(256), 0, stream, kmat, k_h, (long long)m * a / 4, 1.f);
    hipLaunchKernelGGL(k_tcvt, dim3(n / 32, m / 32), dim3(256), 0, stream, vout, vT_h, m, n);

    long long zstride = (long long)Bn * n;
    if (attn_h) {
        // 6) E = exp(q·kᵀ·sc − 5) f16 in GEMM epilogue; sum-only softmax
        hipLaunchKernelGGL((k_gemm4<1>), dim3(Bn / 128, m / 128), dim3(256), 0, stream,
                           q_h, a, k_h, a, attn_h, m, a, (float*)nullptr, 0ll);
        hipLaunchKernelGGL(k_softmax_e, dim3(Bn), dim3(256), 0, stream,
                           attn_h, attn, invs);
        // 7) x_hat = (E @ v) * inv_sum[row], split-K=4 + scaled reduce
        hipLaunchKernelGGL((k_gemm4<0>), dim3(Bn / 128, n / 128, SK), dim3(256), 0, stream,
                           attn_h, m, vT_h, m, xhat, n, m, splitk, zstride);
        hipLaunchKernelGGL(k_redux, dim3(2048), dim3(256), 0, stream,
                           splitk, xhat, (long long)Bn * n / 4, zstride / 4, SK,
                           invs, n / 4);
    } else {
        // fallback (never exercised): f32 logits + legacy softmax + chunked cvt/GEMM
        hipLaunchKernelGGL((k_gemm4<0>), dim3(Bn / 128, m / 128), dim3(256), 0, stream,
                           q_h, a, k_h, a, attn, m, a, (float*)nullptr, 0ll);
        hipLaunchKernelGGL(k_softmax, dim3(Bn), dim3(256), 0, stream, attn, (_Float16*)nullptr, 1.0f);
        _Float16* chunk_h = (_Float16*)splitk;           // 1024*16384*2 = 32MB
        for (int cb = 0; cb < 4; ++cb) {
            const float* src = attn + (long long)cb * 1024 * m;
            hipLaunchKernelGGL(k_cvt, dim3(4096), dim3(256), 0, stream,
                               src, chunk_h, (long long)1024 * m / 4, 1.f);
            hipLaunchKernelGGL((k_gemm4<0>), dim3(1024 / 128, n / 128), dim3(256), 0, stream,
                               chunk_h, m, vT_h, m, xhat + (long long)cb * 1024 * n, n, m,
                               (float*)nullptr, 0ll);
        }
    }
}

// Round 12
// 552.360 us; speedup vs baseline: 1.2260x; 1.0329x over previous
//
#include <hip/hip_runtime.h>
#include <math.h>

typedef _Float16 hlf4 __attribute__((ext_vector_type(4)));
typedef _Float16 hlf8 __attribute__((ext_vector_type(8)));
typedef float f32x4 __attribute__((ext_vector_type(4)));

// async global->LDS, 16B per lane; lds base must be wave-uniform
static __device__ __forceinline__ void gl_lds16(const void* g, void* l) {
    __builtin_amdgcn_global_load_lds(
        (const __attribute__((address_space(1))) unsigned int*)g,
        (__attribute__((address_space(3))) unsigned int*)l, 16, 0, 0);
}

// ---------------- block reductions (deterministic tree order) ----------------
static __device__ __forceinline__ float blk_sum(float v) {
    __shared__ float sm[256];
    int tid = threadIdx.x;
    sm[tid] = v; __syncthreads();
#pragma unroll
    for (int s = 128; s > 0; s >>= 1) {
        if (tid < s) sm[tid] += sm[tid + s];
        __syncthreads();
    }
    float r = sm[0]; __syncthreads();
    return r;
}

static __device__ __forceinline__ float blk_max(float v) {
    __shared__ float sm[256];
    int tid = threadIdx.x;
    sm[tid] = v; __syncthreads();
#pragma unroll
    for (int s = 128; s > 0; s >>= 1) {
        if (tid < s) sm[tid] = fmaxf(sm[tid], sm[tid + s]);
        __syncthreads();
    }
    float r = sm[0]; __syncthreads();
    return r;
}

__global__ __launch_bounds__(256) void k_cinv(
    const float* __restrict__ norms, int m, int n, float* __restrict__ cinv) {
    float s = 0.f;
    for (int i = threadIdx.x; i < m; i += 256) s += norms[i];
    float tot = blk_sum(s);
    if (threadIdx.x == 0) cinv[0] = (float)m * sqrtf((float)n) / tot;  // 1/C
}

// ------- xs = x * (1/C) f32 (output) + UNSCALED f16 copy (LN-invariant) -----
__global__ __launch_bounds__(256) void k_scale2(
    const float* __restrict__ x, const float* __restrict__ cinv,
    float* __restrict__ y, _Float16* __restrict__ yh, long long total4) {
    float c = cinv[0];
    long long i = blockIdx.x * 256ll + threadIdx.x;
    long long stride = (long long)gridDim.x * 256ll;
    for (; i < total4; i += stride) {
        float4 v = ((const float4*)x)[i];
        float4 w = {v.x * c, v.y * c, v.z * c, v.w * c};
        ((float4*)y)[i] = w;
        // q = LN(xs@Wq^T) is invariant to the 1/C scale -> unscaled f16 copy
        hlf4 o = {(_Float16)v.x, (_Float16)v.y, (_Float16)v.z, (_Float16)v.w};
        ((hlf4*)yh)[i] = o;
    }
}

// ---- gather + cvt + fused row-norm (row already in registers; saves a pass) -
__global__ __launch_bounds__(256) void k_gather_cvt(
    const float* __restrict__ X, const int* __restrict__ idx,
    _Float16* __restrict__ out, float* __restrict__ norms, int n) {
    long long r = idx[blockIdx.x];
    const float* src = X + r * (long long)n;
    _Float16* dst = out + (long long)blockIdx.x * n;
    float s = 0.f;
    for (int k = threadIdx.x * 4; k < n; k += 256 * 4) {
        float4 v = *(const float4*)(src + k);
        hlf4 o = {(_Float16)v.x, (_Float16)v.y, (_Float16)v.z, (_Float16)v.w};
        *(hlf4*)(dst + k) = o;
        s = fmaf(v.x, v.x, s); s = fmaf(v.y, v.y, s);
        s = fmaf(v.z, v.z, s); s = fmaf(v.w, v.w, s);
    }
    float tot = blk_sum(s);
    if (threadIdx.x == 0) norms[blockIdx.x] = sqrtf(tot);
}

// ---------------- flat f32 -> f16 with scalar scale ----------------
__global__ __launch_bounds__(256) void k_cvt(
    const float* __restrict__ in, _Float16* __restrict__ out, long long n4,
    float sc) {
    long long i = blockIdx.x * 256ll + threadIdx.x;
    long long stride = (long long)gridDim.x * 256ll;
    for (; i < n4; i += stride) {
        float4 v = ((const float4*)in)[i];
        hlf4 o = {(_Float16)(v.x * sc), (_Float16)(v.y * sc),
                  (_Float16)(v.z * sc), (_Float16)(v.w * sc)};
        ((hlf4*)out)[i] = o;
    }
}

// ---------------- transpose + cvt: in[R][Cc] f32 -> out[Cc][R] f16 ----------
__global__ __launch_bounds__(256) void k_tcvt(
    const float* __restrict__ in, _Float16* __restrict__ out, int R, int Cc) {
    __shared__ _Float16 t[32][34];
    int tx = threadIdx.x & 31, ty = threadIdx.x >> 5;   // ty 0..7
    int c0 = blockIdx.x * 32, r0 = blockIdx.y * 32;
#pragma unroll
    for (int i = 0; i < 32; i += 8)
        t[ty + i][tx] = (_Float16)in[(long long)(r0 + ty + i) * Cc + c0 + tx];
    __syncthreads();
#pragma unroll
    for (int i = 0; i < 32; i += 8)
        out[(long long)(c0 + ty + i) * R + r0 + tx] = t[tx][ty + i];
}

// ================= m97-structure MFMA NT GEMM (128² tile, 4 waves) ==========
// Proven R4 kernel. Block-id handling: HW-linearize (x fastest) -> XCD
// bijective remap -> decompose BY-FASTEST so the blocks sharing an A row
// panel are consecutive on the SAME XCD -> A-panel fetched once into that
// XCD's L2 (kills the 3x A re-fetch seen in R8's FETCH counters).
// MODE: 0 = f32 C (direct or split-K partial); 1 = f16 exp(C-5) epilogue
// (fixed-shift softmax: |S|<=16 by Cauchy-Schwarz on LN rows * 1/sqrt(a)).
template <int MODE>
__global__ __launch_bounds__(256) void k_gemm4(
    const _Float16* __restrict__ A, int lda,
    const _Float16* __restrict__ B, int ldb,
    void* __restrict__ Cc, long long ldc, int K,
    float* __restrict__ part, long long zstride) {
    __shared__ _Float16 Ah[2][4096];
    __shared__ _Float16 Bh[2][4096];
    const int tid = threadIdx.x;

    const int gx = gridDim.x, gy = gridDim.y;
    int lin = blockIdx.x + gx * (blockIdx.y + gy * blockIdx.z);
    const int cpx = (gx * gy * (int)gridDim.z) >> 3;   // nwg always %8==0
    lin = (lin & 7) * cpx + (lin >> 3);                // XCD-contiguous chunks
    const int by = lin % gy;                           // N fastest: A reuse
    const int rest = lin / gy;
    const int bx = rest % gx, bz = rest / gx;

    const long long m0 = (long long)bx * 128;
    const long long n0 = (long long)by * 128;
    const int KC = K / gridDim.z;
    const int kbase = bz * KC;
    const int lane = tid & 63, wv = tid >> 6;
    const int wm = (wv >> 1) * 64, wn = (wv & 1) * 64;
    const int fr = lane & 15, fq = lane >> 4;

    const int s0 = tid, s1 = tid + 256;
    const int r0s = s0 >> 2, r1s = s1 >> 2;
    const int g0 = (((s0 & 3) ^ (r0s & 3)) << 3);
    const int g1 = (((s1 & 3) ^ (r1s & 3)) << 3);
    const _Float16* A0 = A + (m0 + r0s) * (long long)lda + kbase + g0;
    const _Float16* A1 = A + (m0 + r1s) * (long long)lda + kbase + g1;
    const _Float16* B0 = B + (n0 + r0s) * (long long)ldb + kbase + g0;
    const _Float16* B1 = B + (n0 + r1s) * (long long)ldb + kbase + g1;

    f32x4 acc[4][4] = {};

    const int NT = KC / 32;
    {
        gl_lds16(A0, &Ah[0][wv * 512]);
        gl_lds16(A1, &Ah[0][2048 + wv * 512]);
        gl_lds16(B0, &Bh[0][wv * 512]);
        gl_lds16(B1, &Bh[0][2048 + wv * 512]);
    }
    __syncthreads();

    for (int kt = 0; kt < NT; ++kt) {
        const int cur = kt & 1;
        if (kt + 1 < NT) {
            const int nx = cur ^ 1;
            const long long ko = (long long)(kt + 1) * 32;
            gl_lds16(A0 + ko, &Ah[nx][wv * 512]);
            gl_lds16(A1 + ko, &Ah[nx][2048 + wv * 512]);
            gl_lds16(B0 + ko, &Bh[nx][wv * 512]);
            gl_lds16(B1 + ko, &Bh[nx][2048 + wv * 512]);
        }
        hlf8 af[4], bf[4];
#pragma unroll
        for (int i = 0; i < 4; ++i) {
            const int r = wm + i * 16 + fr;
            af[i] = *(const hlf8*)&Ah[cur][r * 32 + ((fq ^ (r & 3)) << 3)];
        }
#pragma unroll
        for (int j = 0; j < 4; ++j) {
            const int r = wn + j * 16 + fr;
            bf[j] = *(const hlf8*)&Bh[cur][r * 32 + ((fq ^ (r & 3)) << 3)];
        }
#pragma unroll
        for (int i = 0; i < 4; ++i)
#pragma unroll
            for (int j = 0; j < 4; ++j)
                acc[i][j] = __builtin_amdgcn_mfma_f32_16x16x32_f16(af[i], bf[j], acc[i][j], 0, 0, 0);
        __syncthreads();
    }

    // C/D layout: col=lane&15, row=(lane>>4)*4+reg (m89-verified)
    if constexpr (MODE == 1) {
        _Float16* op = (_Float16*)Cc;
#pragma unroll
        for (int i = 0; i < 4; ++i)
#pragma unroll
            for (int j = 0; j < 4; ++j) {
                _Float16* cp = op + (m0 + wm + i * 16 + fq * 4) * ldc + (n0 + wn + j * 16 + fr);
#pragma unroll
                for (int r = 0; r < 4; ++r)
                    cp[(long long)r * ldc] = (_Float16)__expf(acc[i][j][r] - 5.0f);
            }
    } else {
        float* outp = (gridDim.z == 1) ? (float*)Cc : (part + (long long)bz * zstride);
#pragma unroll
        for (int i = 0; i < 4; ++i)
#pragma unroll
            for (int j = 0; j < 4; ++j) {
                float* cp = outp + (m0 + wm + i * 16 + fq * 4) * ldc + (n0 + wn + j * 16 + fr);
#pragma unroll
                for (int r = 0; r < 4; ++r) cp[(long long)r * ldc] = acc[i][j][r];
            }
    }
}

// ------- split-K reduction with optional per-row scale: out = inv[row]*Σ ----
__global__ __launch_bounds__(256) void k_redux(
    const float* __restrict__ part, float* __restrict__ out,
    long long n4, long long zs4, int Z,
    const float* __restrict__ invs, int rowdiv4) {
    long long i = blockIdx.x * 256ll + threadIdx.x;
    long long stride = (long long)gridDim.x * 256ll;
    for (; i < n4; i += stride) {
        float4 s = ((const float4*)part)[i];
        for (int z = 1; z < Z; ++z) {
            float4 t = ((const float4*)part)[i + z * zs4];
            s.x += t.x; s.y += t.y; s.z += t.z; s.w += t.w;
        }
        if (invs) {
            float iv = invs[i / rowdiv4];
            s.x *= iv; s.y *= iv; s.z *= iv; s.w *= iv;
        }
        ((float4*)out)[i] = s;
    }
}

// ---------------- row LayerNorm in-place (f32), width W = CNT*256 -----------
template <int CNT>
__global__ __launch_bounds__(256) void k_layernorm(
    float* __restrict__ Y, const float* __restrict__ g,
    const float* __restrict__ b, int W) {
    float* yr = Y + (long long)blockIdx.x * W;
    float v[CNT];
    float s = 0.f;
#pragma unroll
    for (int i = 0; i < CNT; ++i) {
        v[i] = yr[threadIdx.x + (i << 8)];
        s += v[i];
    }
    float mu = blk_sum(s) / (float)W;
    float sq = 0.f;
#pragma unroll
    for (int i = 0; i < CNT; ++i) {
        float d = v[i] - mu;
        sq = fmaf(d, d, sq);
    }
    float var = blk_sum(sq) / (float)W;
    float rs = rsqrtf(var + 1e-5f);
#pragma unroll
    for (int i = 0; i < CNT; ++i) {
        int col = threadIdx.x + (i << 8);
        yr[col] = (v[i] - mu) * rs * g[col] + b[col];
    }
}

// ---- row LayerNorm f32 -> f16 (scaled); for q,k whose f32 isn't an output --
__global__ __launch_bounds__(256) void k_layernorm_h(
    const float* __restrict__ Y, const float* __restrict__ g,
    const float* __restrict__ b, _Float16* __restrict__ outh, int W, float sc) {
    const float* yr = Y + (long long)blockIdx.x * W;
    _Float16* orow = outh + (long long)blockIdx.x * W;
    float v = yr[threadIdx.x];                       // W == 256 here
    float mu = blk_sum(v) / (float)W;
    float d = v - mu;
    float var = blk_sum(d * d) / (float)W;
    float rs = rsqrtf(var + 1e-5f);
    orow[threadIdx.x] = (_Float16)((d * rs * g[threadIdx.x] + b[threadIdx.x]) * sc);
}

// -------- sum-only softmax over E = exp(S-5) f16, W = 16384 -----------------
// writes attn = E*inv (f32) and invs[row] = 1/sum for the x_hat epilogue.
__global__ __launch_bounds__(256) void k_softmax_e(
    const _Float16* __restrict__ E, float* __restrict__ attnf,
    float* __restrict__ invs) {
    const _Float16* er = E + (long long)blockIdx.x * 16384;
    float* ar = attnf + (long long)blockIdx.x * 16384;
    float4 r[16];
    float sum = 0.f;
#pragma unroll
    for (int i = 0; i < 16; ++i) {
        hlf4 h = ((const hlf4*)er)[threadIdx.x + (i << 8)];
        float4 t = {(float)h[0], (float)h[1], (float)h[2], (float)h[3]};
        r[i] = t;
        sum += t.x + t.y + t.z + t.w;
    }
    sum = blk_sum(sum);
    float inv = 1.0f / sum;
    if (threadIdx.x == 0) invs[blockIdx.x] = inv;
#pragma unroll
    for (int i = 0; i < 16; ++i) {
        float4 t = r[i];
        t.x *= inv; t.y *= inv; t.z *= inv; t.w *= inv;
        ((float4*)ar)[threadIdx.x + (i << 8)] = t;
    }
}

extern "C" void kernel_launch(void* const* d_in, const int* in_sizes, int n_in,
                              void* d_out, int out_size, void* d_ws, size_t ws_size,
                              hipStream_t stream) {
    const float* x      = (const float*)d_in[0];
    const float* X_data = (const float*)d_in[1];
    const int*   midx   = (const int*)d_in[2];
    const float* W_q    = (const float*)d_in[3];
    const float* W_k    = (const float*)d_in[4];
    const float* W_v    = (const float*)d_in[5];
    const float* g_q    = (const float*)d_in[6];
    const float* b_q    = (const float*)d_in[7];
    const float* g_k    = (const float*)d_in[8];
    const float* b_k    = (const float*)d_in[9];
    const float* g_v    = (const float*)d_in[10];
    const float* b_v    = (const float*)d_in[11];

    const int n  = in_sizes[10];        // 1024
    const int a  = in_sizes[6];         // 256
    const int m  = in_sizes[2];         // 16384
    const int Bn = in_sizes[0] / n;     // 4096

    // output layout: xs | x_hat | attn | v
    float* out  = (float*)d_out;
    float* xs   = out;
    float* xhat = xs + (long long)Bn * n;
    float* attn = xhat + (long long)Bn * n;
    float* vout = attn + (long long)Bn * m;

    // workspace carving (256B aligned). [qmat .. k_h] (~73 MB) is dead before
    // the x_hat GEMM, so the 64 MB split-K partial buffer aliases it.
    // invs lives OUTSIDE the aliased span (read after partials written).
    char* wp = (char*)d_ws;
    auto carve = [&](size_t bytes) -> char* {
        char* r = wp; wp += (bytes + 255) & ~(size_t)255; return r;
    };
    float*     norms = (float*)carve((size_t)m * 4);
    float*     cinv  = (float*)carve(16);
    float*     invs  = (float*)carve((size_t)Bn * 4);
    char*      alias0 = wp;
    float*     qmat  = (float*)carve((size_t)Bn * a * 4);
    float*     kmat  = (float*)carve((size_t)m * a * 4);
    _Float16*  xs_h  = (_Float16*)carve((size_t)Bn * n * 2);
    _Float16*  Xc_h  = (_Float16*)carve((size_t)m * n * 2);
    _Float16*  Wq_h  = (_Float16*)carve((size_t)a * n * 2);
    _Float16*  Wk_h  = (_Float16*)carve((size_t)a * n * 2);
    _Float16*  Wv_h  = (_Float16*)carve((size_t)n * n * 2);
    _Float16*  q_h   = (_Float16*)carve((size_t)Bn * a * 2);
    _Float16*  k_h   = (_Float16*)carve((size_t)m * a * 2);
    float*     splitk = (float*)alias0;
    const int  SK = 4;                                    // SK*Bn*n*4 = 64MB <= 73MB
    _Float16*  vT_h  = (_Float16*)carve((size_t)n * m * 2);
    size_t used = (size_t)(wp - (char*)d_ws);
    _Float16* attn_h = nullptr;
    if (ws_size >= used + (size_t)Bn * m * 2 + 256)
        attn_h = (_Float16*)carve((size_t)Bn * m * 2);

    // 1) gather + cvt + fused row norms; then 1/C
    hipLaunchKernelGGL(k_gather_cvt, dim3(m), dim3(256), 0, stream,
                       X_data, midx, Xc_h, norms, n);
    hipLaunchKernelGGL(k_cinv, dim3(1), dim3(256), 0, stream, norms, m, n, cinv);

    // 2) xs = x/C (f32 output) + unscaled f16 copy for q projection
    hipLaunchKernelGGL(k_scale2, dim3(2048), dim3(256), 0, stream,
                       x, cinv, xs, xs_h, (long long)Bn * n / 4);

    // 3) weights -> f16
    hipLaunchKernelGGL(k_cvt, dim3(256), dim3(256), 0, stream, W_q, Wq_h, (long long)a * n / 4, 1.f);
    hipLaunchKernelGGL(k_cvt, dim3(256), dim3(256), 0, stream, W_k, Wk_h, (long long)a * n / 4, 1.f);
    hipLaunchKernelGGL(k_cvt, dim3(1024), dim3(256), 0, stream, W_v, Wv_h, (long long)n * n / 4, 1.f);

    // 4) projections (all on proven 128² kernel, A-reuse block ordering)
    hipLaunchKernelGGL((k_gemm4<0>), dim3(Bn / 128, a / 128), dim3(256), 0, stream,
                       xs_h, n, Wq_h, n, qmat, a, n, (float*)nullptr, 0ll);
    hipLaunchKernelGGL((k_gemm4<0>), dim3(m / 128, a / 128), dim3(256), 0, stream,
                       Xc_h, n, Wk_h, n, kmat, a, n, (float*)nullptr, 0ll);
    hipLaunchKernelGGL((k_gemm4<0>), dim3(m / 128, n / 128), dim3(256), 0, stream,
                       Xc_h, n, Wv_h, n, vout, n, n, (float*)nullptr, 0ll);

    // 5) LayerNorms: q,k fused f32->f16 (scale folded; f32 never re-read);
    //    v in-place f32 (required output) + transposed f16 copy
    float sc = 1.0f / sqrtf((float)a);
    hipLaunchKernelGGL(k_layernorm_h, dim3(Bn), dim3(256), 0, stream,
                       qmat, g_q, b_q, q_h, a, sc);
    hipLaunchKernelGGL(k_layernorm_h, dim3(m), dim3(256), 0, stream,
                       kmat, g_k, b_k, k_h, a, 1.f);
    hipLaunchKernelGGL(k_layernorm<4>, dim3(m), dim3(256), 0, stream, vout, g_v, b_v, n);
    hipLaunchKernelGGL(k_tcvt, dim3(n / 32, m / 32), dim3(256), 0, stream, vout, vT_h, m, n);

    long long zstride = (long long)Bn * n;
    if (attn_h) {
        // 6) E = exp(q·kᵀ·sc − 5) f16 in GEMM epilogue; sum-only softmax
        hipLaunchKernelGGL((k_gemm4<1>), dim3(Bn / 128, m / 128), dim3(256), 0, stream,
                           q_h, a, k_h, a, attn_h, m, a, (float*)nullptr, 0ll);
        hipLaunchKernelGGL(k_softmax_e, dim3(Bn), dim3(256), 0, stream,
                           attn_h, attn, invs);
        // 7) x_hat = (E @ v) * inv_sum[row], split-K=4 + scaled reduce
        hipLaunchKernelGGL((k_gemm4<0>), dim3(Bn / 128, n / 128, SK), dim3(256), 0, stream,
                           attn_h, m, vT_h, m, xhat, n, m, splitk, zstride);
        hipLaunchKernelGGL(k_redux, dim3(2048), dim3(256), 0, stream,
                           splitk, xhat, (long long)Bn * n / 4, zstride / 4, SK,
                           invs, n / 4);
    } else {
        // fallback (never exercised; ws has always fit): chunked E in splitk
        // region: process Bn in 4 chunks -> E chunk f16 (32MB), sum+attn, GEMM.
        _Float16* chunk_h = (_Float16*)splitk;           // 1024*16384*2 = 32MB
        for (int cb = 0; cb < 4; ++cb) {
            hipLaunchKernelGGL((k_gemm4<1>), dim3(1024 / 128, m / 128), dim3(256), 0, stream,
                               q_h + (long long)cb * 1024 * a, a, k_h, a,
                               chunk_h, m, a, (float*)nullptr, 0ll);
            hipLaunchKernelGGL(k_softmax_e, dim3(1024), dim3(256), 0, stream,
                               chunk_h, attn + (long long)cb * 1024 * m,
                               invs + (long long)cb * 1024);
            hipLaunchKernelGGL((k_gemm4<0>), dim3(1024 / 128, n / 128), dim3(256), 0, stream,
                               chunk_h, m, vT_h, m, xhat + (long long)cb * 1024 * n, n, m,
                               (float*)nullptr, 0ll);
        }
        // apply inv row-scale to xhat chunks (reuse redux with Z=1)
        hipLaunchKernelGGL(k_redux, dim3(2048), dim3(256), 0, stream,
                           xhat, xhat, (long long)Bn * n / 4, 0ll, 1, invs, n / 4);
    }
}